// Round 10
// baseline (624.845 us; speedup 1.0000x reference)
//
#include <hip/hip_runtime.h>

// AttentionRNN: B=64, NUM=8, TC=64, H=128. bn=512 sequences.
// R10: 512 thr/block (8 waves/CU, 2/SIMD), 256 blocks, 2 seqs/block.
// Phase mappings all from validated kernels (R5/R8/R9). D = 384 threads,
// mat x col-quad x row-half, weights global->reg in 8-row chunks (R9 pattern),
// row-halves combined via shfl_xor(1). Designed to ~105 VGPR (<128 cap).

#define OFF_ATTW  0        // [128][64] att_w
#define OFF_U     8192     // [64][64] att_u (prologue only)
#define OFF_HST   12288    // [2][128]
#define OFF_HPART 12544    // [2][64]
#define OFF_XTV   12672    // [2][128]
#define OFF_XMRM  12928    // [mat][seq][384]
#define OFF_VV    14464    // [64]
#define OFF_RED   14528    // [8]
#define LDS_FLOATS 14536   // ~58 KB

#define FMA4(ACC, W, S) do { (ACC).x += (W).x*(S); (ACC).y += (W).y*(S); \
                             (ACC).z += (W).z*(S); (ACC).w += (W).w*(S); } while(0)

__global__ __launch_bounds__(512)
void attn_gru_kernel(const float* __restrict__ x, const float* __restrict__ att_v,
                     const float* __restrict__ att_w, const float* __restrict__ att_u,
                     const float* __restrict__ gk, const float* __restrict__ grk,
                     const float* __restrict__ gbias, float* __restrict__ out) {
    __shared__ float lds[LDS_FLOATS];
    const int tid = threadIdx.x;
    const int bn0 = blockIdx.x * 2;

    // ---- stage att_w, U, v; zero h
    for (int i = tid; i < 8192; i += 512) lds[OFF_ATTW + i] = att_w[i];
    for (int i = tid; i < 4096; i += 512) lds[OFF_U + i] = att_u[i];
    if (tid < 64)  lds[OFF_VV + tid] = att_v[tid];
    if (tid < 256) lds[OFF_HST + tid] = 0.0f;
    __syncthreads();

    // ---- thread mappings (validated: A from R8, C/E from R5, D from R8/R9)
    const int cseq = tid >> 8;            // seq for A/C
    const int chh  = (tid >> 1) & 127;    // feature (C)
    const int csh  = tid & 1;             // s-half (C)
    const int as   = (tid >> 2) & 63;     // phase A: s
    const int aq   = tid & 3;             // phase A: h-quarter (adjacent lanes)
    // phase D: 384 threads = mat(2) x col-quad(96) x row-half(2, adjacent lanes)
    const int dact = (tid < 384);
    const int dm   = (tid >= 192) ? 1 : 0;
    const int du   = tid - dm * 192;      // 0..191
    const int dcq  = du >> 1;             // col-quad: cols 4dcq..4dcq+3
    const int drh  = du & 1;              // row half: rows drh*64..drh*64+63
    const int din  = dm ? OFF_HST : OFF_XTV;
    const float* Wm = (dm ? grk : gk) + (size_t)(drh * 64) * 384 + 4 * dcq;
    float4 bias4 = make_float4(0.f, 0.f, 0.f, 0.f);
    if (dact) bias4 = *(const float4*)(gbias + dm * 384 + 4 * dcq);

    // ---- prologue: uproj half in registers (32/thread) [R5-validated]
    float up[32];
    #pragma unroll
    for (int k = 0; k < 32; ++k) up[k] = 0.0f;
    {
        const float* xb = x + (size_t)(bn0 + cseq) * 8192 + chh;
        for (int t = 0; t < 64; ++t) {
            float xvp = xb[t * 128];
            const float4* Ur = (const float4*)(lds + OFF_U + t * 64 + csh * 32);
            #pragma unroll
            for (int k4 = 0; k4 < 8; ++k4) {
                float4 u = Ur[k4];
                up[k4*4+0] += xvp * u.x; up[k4*4+1] += xvp * u.y;
                up[k4*4+2] += xvp * u.z; up[k4*4+3] += xvp * u.w;
            }
        }
    }
    float sv = 0.0f;
    #pragma unroll
    for (int k = 0; k < 32; ++k) sv += lds[OFF_VV + csh * 32 + k];

    __syncthreads();

    const float* xcol = x + (size_t)(bn0 + cseq) * 8192 + chh;

    #pragma unroll 1
    for (int t = 0; t < 64; ++t) {
        float xv = xcol[t * 128];

        // ---- A: h_part[s] partials over h-quarters, shfl-reduced [R8-validated]
        {
            float pa = 0.0f;
            const float4* hb4 = (const float4*)(lds + OFF_HST + cseq * 128 + aq * 32);
            const float* wgl = lds + OFF_ATTW + aq * 32 * 64 + as;
            #pragma unroll
            for (int k4 = 0; k4 < 8; ++k4) {
                float4 hv = hb4[k4];
                pa += hv.x * wgl[(k4*4+0)*64] + hv.y * wgl[(k4*4+1)*64]
                    + hv.z * wgl[(k4*4+2)*64] + hv.w * wgl[(k4*4+3)*64];
            }
            pa += __shfl_xor(pa, 1);
            pa += __shfl_xor(pa, 2);
            if (aq == 0) lds[OFF_HPART + cseq * 64 + as] = pa;
        }
        __syncthreads();

        // ---- C: e = sum_s tanh(hp+up)*v (s-half per lane pair) [R5-validated]
        float den = 0.0f;
        {
            const float4* hp4 = (const float4*)(lds + OFF_HPART + cseq * 64 + csh * 32);
            const float4* vv4 = (const float4*)(lds + OFF_VV + csh * 32);
            #pragma unroll
            for (int k4 = 0; k4 < 8; ++k4) {
                float4 hp = hp4[k4];
                float4 v4 = vv4[k4];
                den += v4.x * __fdividef(1.0f, __expf(2.0f * (hp.x + up[k4*4+0])) + 1.0f);
                den += v4.y * __fdividef(1.0f, __expf(2.0f * (hp.y + up[k4*4+1])) + 1.0f);
                den += v4.z * __fdividef(1.0f, __expf(2.0f * (hp.z + up[k4*4+2])) + 1.0f);
                den += v4.w * __fdividef(1.0f, __expf(2.0f * (hp.w + up[k4*4+3])) + 1.0f);
            }
        }
        float ep = sv - 2.0f * den;
        float e  = ep + __shfl_xor(ep, 1);      // both pair lanes hold full e
        float p  = __expf(e);                   // |e| <= sum|v| ~ 5: fp32-safe
        float wsum = p;
        #pragma unroll
        for (int off = 1; off <= 32; off <<= 1) wsum += __shfl_xor(wsum, off);
        if ((tid & 63) == 0) lds[OFF_RED + (tid >> 6)] = wsum;  // each hh counted 2x
        __syncthreads();
        float denom = 0.5f * (lds[OFF_RED + cseq * 4 + 0] + lds[OFF_RED + cseq * 4 + 1]
                            + lds[OFF_RED + cseq * 4 + 2] + lds[OFF_RED + cseq * 4 + 3]);
        float av = __fdividef(p, denom);
        lds[OFF_XTV + cseq * 128 + chh] = av * xv;   // pair lanes write same value
        __syncthreads();

        // ---- D: xm/rm. 8 chunks x 8 float4 weight loads in flight (R9 pattern).
        if (dact) {
            float4 acc0 = make_float4(0.f, 0.f, 0.f, 0.f);
            float4 acc1 = make_float4(0.f, 0.f, 0.f, 0.f);
            #pragma unroll 1
            for (int c = 0; c < 8; ++c) {
                float4 w[8];
                #pragma unroll
                for (int r = 0; r < 8; ++r)
                    w[r] = *(const float4*)(Wm + (size_t)(c * 8 + r) * 384);
                const float* ib = lds + din + drh * 64 + c * 8;
                float4 p0 = *(const float4*)(ib);
                float4 p1 = *(const float4*)(ib + 4);
                float4 q0 = *(const float4*)(ib + 128);
                float4 q1 = *(const float4*)(ib + 132);
                FMA4(acc0, w[0], p0.x); FMA4(acc1, w[0], q0.x);
                FMA4(acc0, w[1], p0.y); FMA4(acc1, w[1], q0.y);
                FMA4(acc0, w[2], p0.z); FMA4(acc1, w[2], q0.z);
                FMA4(acc0, w[3], p0.w); FMA4(acc1, w[3], q0.w);
                FMA4(acc0, w[4], p1.x); FMA4(acc1, w[4], q1.x);
                FMA4(acc0, w[5], p1.y); FMA4(acc1, w[5], q1.y);
                FMA4(acc0, w[6], p1.z); FMA4(acc1, w[6], q1.z);
                FMA4(acc0, w[7], p1.w); FMA4(acc1, w[7], q1.w);
            }
            // combine row-halves (adjacent lanes), store complete dots + bias
            acc0.x += __shfl_xor(acc0.x, 1); acc0.y += __shfl_xor(acc0.y, 1);
            acc0.z += __shfl_xor(acc0.z, 1); acc0.w += __shfl_xor(acc0.w, 1);
            acc1.x += __shfl_xor(acc1.x, 1); acc1.y += __shfl_xor(acc1.y, 1);
            acc1.z += __shfl_xor(acc1.z, 1); acc1.w += __shfl_xor(acc1.w, 1);
            if (drh == 0) {
                *(float4*)(lds + OFF_XMRM + (dm * 2 + 0) * 384 + 4 * dcq) =
                    make_float4(acc0.x + bias4.x, acc0.y + bias4.y,
                                acc0.z + bias4.z, acc0.w + bias4.w);
                *(float4*)(lds + OFF_XMRM + (dm * 2 + 1) * 384 + 4 * dcq) =
                    make_float4(acc1.x + bias4.x, acc1.y + bias4.y,
                                acc1.z + bias4.z, acc1.w + bias4.w);
            }
        }
        __syncthreads();

        // ---- E: gates + h update [R5-validated]
        if (tid < 256) {
            const int eseq = tid >> 7, ehh = tid & 127;
            const float* xm = lds + OFF_XMRM + (0 * 2 + eseq) * 384;
            const float* rm = lds + OFF_XMRM + (1 * 2 + eseq) * 384;
            float xz = xm[ehh], xr = xm[128 + ehh], xh_ = xm[256 + ehh];
            float rz = rm[ehh], rr = rm[128 + ehh], rh = rm[256 + ehh];
            float z = __fdividef(1.0f, 1.0f + __expf(-(xz + rz)));
            float r = __fdividef(1.0f, 1.0f + __expf(-(xr + rr)));
            float hc = xh_ + r * rh;
            hc = hc > 0.0f ? hc : 0.0f;
            float hold = lds[OFF_HST + eseq * 128 + ehh];
            lds[OFF_HST + eseq * 128 + ehh] = z * hold + (1.0f - z) * hc;
        }
        __syncthreads();
    }

    if (tid < 256) {
        const int eseq = tid >> 7, ehh = tid & 127;
        out[(size_t)(bn0 + eseq) * 128 + ehh] = lds[OFF_HST + eseq * 128 + ehh];
    }
}

extern "C" void kernel_launch(void* const* d_in, const int* in_sizes, int n_in,
                              void* d_out, int out_size, void* d_ws, size_t ws_size,
                              hipStream_t stream) {
    (void)in_sizes; (void)n_in; (void)out_size; (void)d_ws; (void)ws_size;
    const float* x      = (const float*)d_in[0];
    const float* att_v  = (const float*)d_in[1];
    const float* att_w  = (const float*)d_in[2];
    const float* att_u  = (const float*)d_in[3];
    const float* gk     = (const float*)d_in[4];
    const float* grk    = (const float*)d_in[5];
    const float* gbias  = (const float*)d_in[6];
    float* out = (float*)d_out;
    hipLaunchKernelGGL(attn_gru_kernel, dim3(256), dim3(512), 0, stream,
                       x, att_v, att_w, att_u, gk, grk, gbias, out);
}